// Round 3
// baseline (259.024 us; speedup 1.0000x reference)
//
#include <hip/hip_runtime.h>
#include <math.h>

// out[i][j] = | prod_w cos((x[i][w]+y[j][w])/2 + theta[w]) |
//           = | prod_w ( cos(ax_w)cos(ay_w) - sin(ax_w)sin(ay_w) ) |,
//   ax_w = 0.5*x[i][w] + 0.5*theta[w],  ay_w = 0.5*y[j][w] + 0.5*theta[w]
// (RX(x)RX(th)=RX(x+th) -> product state; CNOT ladder is a basis permutation that
//  cancels in the non-conjugated bilinear form; inner product factorizes per wire.)
//
// Single fused streaming kernel: all trig computed in registers (A-side once per
// block, B-side per tile), no LDS, no barrier, no workspace. Each block writes a
// 16 x 2048 output panel (8 column tiles). Write roofline: 268 MB @ ~6.6 TB/s ≈ 41 us;
// trans-pipe total ~7 us and VALU ~15 us hide under the store stream.

#define BM 16    // output rows per block
#define BN 256   // output cols per tile (one float4 per lane)
#define TJ 8     // column tiles per block -> block writes 16 x 2048

__global__ __launch_bounds__(256) void qk_stream(
    const float* __restrict__ x, const float* __restrict__ y,
    const float* __restrict__ theta, float* __restrict__ out,
    int Nx, int Ny)
{
    const int tid = threadIdx.x;
    const int tx = tid & 63;          // lane -> 4 consecutive output cols
    const int ty = tid >> 6;          // wave -> 4 consecutive output rows
    const int i0 = blockIdx.y * BM;
    const int j0 = blockIdx.x * (BN * TJ);
    const int r0 = i0 + ty * 4;

    const float th0 = 0.5f * theta[0], th1 = 0.5f * theta[1];
    const float th2 = 0.5f * theta[2], th3 = 0.5f * theta[3];

    // A-side trig: 4 rows (wave-uniform address -> broadcast load), 4 wires.
    // 16 sincos per thread, once per block; values live in registers for all tiles.
    float ca[4][4], sa[4][4];         // [wire][row]
    #pragma unroll
    for (int i = 0; i < 4; ++i) {
        const float4 x4 = ((const float4*)x)[r0 + i];
        __sincosf(0.5f * x4.x + th0, &sa[0][i], &ca[0][i]);
        __sincosf(0.5f * x4.y + th1, &sa[1][i], &ca[1][i]);
        __sincosf(0.5f * x4.z + th2, &sa[2][i], &ca[2][i]);
        __sincosf(0.5f * x4.w + th3, &sa[3][i], &ca[3][i]);
    }

    #pragma unroll 2
    for (int t = 0; t < TJ; ++t) {
        const int j = j0 + t * BN + tx * 4;

        // B-side: each thread loads the 4 y-rows it consumes (wave reads 4 KiB
        // contiguous; y is cache-resident) and computes their trig in registers.
        float cb[4][4], sb[4][4];     // [wire][col]
        #pragma unroll
        for (int jj = 0; jj < 4; ++jj) {
            const float4 y4 = ((const float4*)y)[j + jj];
            __sincosf(0.5f * y4.x + th0, &sb[0][jj], &cb[0][jj]);
            __sincosf(0.5f * y4.y + th1, &sb[1][jj], &cb[1][jj]);
            __sincosf(0.5f * y4.z + th2, &sb[2][jj], &cb[2][jj]);
            __sincosf(0.5f * y4.w + th3, &sb[3][jj], &cb[3][jj]);
        }

        float acc[4][4];
        #pragma unroll
        for (int i = 0; i < 4; ++i) {
            #pragma unroll
            for (int jj = 0; jj < 4; ++jj) {
                const float t0 = fmaf(ca[0][i], cb[0][jj], -(sa[0][i] * sb[0][jj]));
                const float t1 = fmaf(ca[1][i], cb[1][jj], -(sa[1][i] * sb[1][jj]));
                const float t2 = fmaf(ca[2][i], cb[2][jj], -(sa[2][i] * sb[2][jj]));
                const float t3 = fmaf(ca[3][i], cb[3][jj], -(sa[3][i] * sb[3][jj]));
                acc[i][jj] = fabsf((t0 * t1) * (t2 * t3));
            }
        }

        // 4 coalesced float4 stores (1 KiB contiguous per wave-store).
        #pragma unroll
        for (int i = 0; i < 4; ++i) {
            float4 o;
            o.x = acc[i][0]; o.y = acc[i][1]; o.z = acc[i][2]; o.w = acc[i][3];
            *(float4*)&out[(size_t)(r0 + i) * Ny + j] = o;
        }
    }
}

// ---------------- fallback: previous verified kernel (non-divisible shapes) ----
__global__ __launch_bounds__(256) void qk_fallback(
    const float* __restrict__ x, const float* __restrict__ y,
    const float* __restrict__ theta, float* __restrict__ out,
    int Bx, int By)
{
    __shared__ float at[8][BM];
    __shared__ float bt[8][BN];

    const int tid = threadIdx.x;
    const int i0 = blockIdx.y * BM;
    const int j0 = blockIdx.x * BN;

    const float th0 = 0.5f * theta[0];
    const float th1 = 0.5f * theta[1];
    const float th2 = 0.5f * theta[2];
    const float th3 = 0.5f * theta[3];

    {
        const float4 y4 = ((const float4*)y)[j0 + tid];
        float s, c;
        __sincosf(0.5f * y4.x + th0, &s, &c); bt[0][tid] = c; bt[4][tid] = s;
        __sincosf(0.5f * y4.y + th1, &s, &c); bt[1][tid] = c; bt[5][tid] = s;
        __sincosf(0.5f * y4.z + th2, &s, &c); bt[2][tid] = c; bt[6][tid] = s;
        __sincosf(0.5f * y4.w + th3, &s, &c); bt[3][tid] = c; bt[7][tid] = s;
    }
    if (tid < BM) {
        const float4 x4 = ((const float4*)x)[i0 + tid];
        float s, c;
        __sincosf(0.5f * x4.x + th0, &s, &c); at[0][tid] = c; at[4][tid] = s;
        __sincosf(0.5f * x4.y + th1, &s, &c); at[1][tid] = c; at[5][tid] = s;
        __sincosf(0.5f * x4.z + th2, &s, &c); at[2][tid] = c; at[6][tid] = s;
        __sincosf(0.5f * x4.w + th3, &s, &c); at[3][tid] = c; at[7][tid] = s;
    }
    __syncthreads();

    const int tx = tid & 63;
    const int ty = tid >> 6;

    float acc[4][4];
    #pragma unroll
    for (int w = 0; w < 4; ++w) {
        const float4 ca = ((const float4*)&at[w][0])[ty];
        const float4 sa = ((const float4*)&at[w + 4][0])[ty];
        const float4 cb = ((const float4*)&bt[w][0])[tx];
        const float4 sb = ((const float4*)&bt[w + 4][0])[tx];

        const float cai[4] = {ca.x, ca.y, ca.z, ca.w};
        const float sai[4] = {sa.x, sa.y, sa.z, sa.w};
        const float cbj[4] = {cb.x, cb.y, cb.z, cb.w};
        const float sbj[4] = {sb.x, sb.y, sb.z, sb.w};

        #pragma unroll
        for (int i = 0; i < 4; ++i) {
            #pragma unroll
            for (int j = 0; j < 4; ++j) {
                const float t = fmaf(cai[i], cbj[j], -(sai[i] * sbj[j]));
                acc[i][j] = (w == 0) ? t : acc[i][j] * t;
            }
        }
    }

    #pragma unroll
    for (int i = 0; i < 4; ++i) {
        const int row = i0 + ty * 4 + i;
        float4 o;
        o.x = fabsf(acc[i][0]);
        o.y = fabsf(acc[i][1]);
        o.z = fabsf(acc[i][2]);
        o.w = fabsf(acc[i][3]);
        ((float4*)&out[(size_t)row * By + j0])[tx] = o;
    }
}

extern "C" void kernel_launch(void* const* d_in, const int* in_sizes, int n_in,
                              void* d_out, int out_size, void* d_ws, size_t ws_size,
                              hipStream_t stream) {
    (void)n_in; (void)out_size; (void)d_ws; (void)ws_size;
    const float* x     = (const float*)d_in[0];
    const float* y     = (const float*)d_in[1];
    const float* theta = (const float*)d_in[2];
    float* out = (float*)d_out;

    const int Bx = in_sizes[0] / 4;  // 8192
    const int By = in_sizes[1] / 4;  // 8192

    if ((By % (BN * TJ)) == 0 && (Bx % BM) == 0) {
        dim3 grid(By / (BN * TJ), Bx / BM);   // (4, 512) = 2048 blocks
        qk_stream<<<grid, dim3(256), 0, stream>>>(x, y, theta, out, Bx, By);
    } else {
        dim3 grid(By / BN, Bx / BM);
        qk_fallback<<<grid, dim3(256), 0, stream>>>(x, y, theta, out, Bx, By);
    }
}